// Round 1
// baseline (509.252 us; speedup 1.0000x reference)
//
#include <hip/hip_runtime.h>
#include <math.h>

#define BB 8
#define NN 2048
#define FF 64
#define EPSV 1e-5f
#define EMB_SZ (BB * NN * FF)

// workspace layout (floats)
#define WS_SQ    0
#define WS_ASUM  (BB * NN)            // 16384
#define WS_ASQ   (WS_ASUM + BB * FF)  // 16896
#define WS_MEAN  (WS_ASQ + BB * FF)   // 17408
#define WS_RSTD  (WS_MEAN + BB * FF)  // 17920

// ---------------------------------------------------------------------------
// Kernel 1: per-row squared norm (sq) + per-(b,f) partial sums for mean/var.
// grid (16, B), block 256: each block does 128 rows; 64-lane groups own rows.
// emb_in is pre-masked (rows >= nb are zero), so unmasked sums == masked sums.
// ---------------------------------------------------------------------------
__global__ __launch_bounds__(256) void k_stats(const float* __restrict__ emb,
                                               float* __restrict__ sq,
                                               float* __restrict__ asum,
                                               float* __restrict__ asq) {
    const int b    = blockIdx.y;
    const int lane = threadIdx.x & 63;
    const int grp  = threadIdx.x >> 6;
    const int base_i = blockIdx.x << 7;

    float s = 0.f, q = 0.f;
    for (int it = 0; it < 32; ++it) {
        const int i = base_i + (it << 2) + grp;
        const float x = emb[((size_t)(b * NN + i) << 6) + lane];
        const float x2 = x * x;
        s += x;
        q += x2;
        float r = x2;  // row reduction across the 64-lane group
        r += __shfl_xor(r, 1);
        r += __shfl_xor(r, 2);
        r += __shfl_xor(r, 4);
        r += __shfl_xor(r, 8);
        r += __shfl_xor(r, 16);
        r += __shfl_xor(r, 32);
        if (lane == 0) sq[b * NN + i] = r;
    }
    __shared__ float redS[4][64];
    __shared__ float redQ[4][64];
    redS[grp][lane] = s;
    redQ[grp][lane] = q;
    __syncthreads();
    if (threadIdx.x < 64) {
        const float ts = redS[0][lane] + redS[1][lane] + redS[2][lane] + redS[3][lane];
        const float tq = redQ[0][lane] + redQ[1][lane] + redQ[2][lane] + redQ[3][lane];
        atomicAdd(&asum[(b << 6) + lane], ts);
        atomicAdd(&asq[(b << 6) + lane], tq);
    }
}

// ---------------------------------------------------------------------------
// Kernel 2: finalize mean / rstd.  1 block, 512 threads (= B*F).
// var = Q/cnt - mean^2  (exact given pre-masked input).
// ---------------------------------------------------------------------------
__global__ void k_finalize(const float* __restrict__ asum, const float* __restrict__ asq,
                           const int* __restrict__ nbp,
                           float* __restrict__ mean, float* __restrict__ rstd) {
    const int t = threadIdx.x;       // 0..511
    const int b = t >> 6;
    const float cnt = fmaxf((float)nbp[b], 1.f);
    const float m = asum[t] / cnt;
    float v = asq[t] / cnt - m * m;
    v = fmaxf(v, 0.f);
    mean[t] = m;
    rstd[t] = rsqrtf(v + EPSV);
}

// ---------------------------------------------------------------------------
// Kernel 3: adj = (w0*adj_in + w1*exp(-max(d2,0)/sigma)) * adj_mask
// 128x128 tile per block, K=64 staged in two 32-slices (LDS < 64 KB).
// Thread (tx,ty) owns an 8x8 register tile split as {ty*4..+4, 64+ty*4..+4} x
// {tx*4..+4, 64+tx*4..+4}  (float4-friendly, <=2-way LDS bank aliasing).
// ---------------------------------------------------------------------------
__global__ __launch_bounds__(256) void k_adj(const float* __restrict__ emb,
                                             const float* __restrict__ adj_in,
                                             const float* __restrict__ adj_mask,
                                             const float* __restrict__ sq,
                                             const float* __restrict__ sigp,
                                             const float* __restrict__ cw,
                                             float* __restrict__ adj_out) {
    __shared__ __align__(16) float As[32][132];  // [k][i]
    __shared__ __align__(16) float Bs[32][132];  // [k][j]
    const int b  = blockIdx.z;
    const int i0 = blockIdx.y << 7;
    const int j0 = blockIdx.x << 7;
    const int tid = threadIdx.x;
    const int tx = tid & 15, ty = tid >> 4;
    const int srow = tid & 31;
    const int scb  = (tid >> 5) << 2;  // 0,4,...,28
    const int bN = b * NN;

    float acc[8][8];
#pragma unroll
    for (int u = 0; u < 8; ++u)
#pragma unroll
        for (int v = 0; v < 8; ++v) acc[u][v] = 0.f;

    for (int kt = 0; kt < FF; kt += 32) {
#pragma unroll
        for (int p = 0; p < 4; ++p) {
            const int row = srow + (p << 5);  // 0..127
            const float4 a  = *(const float4*)(emb + ((size_t)(bN + i0 + row) << 6) + kt + scb);
            const float4 bb = *(const float4*)(emb + ((size_t)(bN + j0 + row) << 6) + kt + scb);
            As[scb + 0][row] = a.x;  As[scb + 1][row] = a.y;
            As[scb + 2][row] = a.z;  As[scb + 3][row] = a.w;
            Bs[scb + 0][row] = bb.x; Bs[scb + 1][row] = bb.y;
            Bs[scb + 2][row] = bb.z; Bs[scb + 3][row] = bb.w;
        }
        __syncthreads();
#pragma unroll 4
        for (int k = 0; k < 32; ++k) {
            const float4 a0 = *(const float4*)&As[k][(ty << 2)];
            const float4 a1 = *(const float4*)&As[k][64 + (ty << 2)];
            const float4 b0 = *(const float4*)&Bs[k][(tx << 2)];
            const float4 b1 = *(const float4*)&Bs[k][64 + (tx << 2)];
            const float av[8] = {a0.x, a0.y, a0.z, a0.w, a1.x, a1.y, a1.z, a1.w};
            const float bv[8] = {b0.x, b0.y, b0.z, b0.w, b1.x, b1.y, b1.z, b1.w};
#pragma unroll
            for (int u = 0; u < 8; ++u)
#pragma unroll
                for (int v = 0; v < 8; ++v)
                    acc[u][v] = fmaf(av[u], bv[v], acc[u][v]);
        }
        __syncthreads();
    }

    const float inv_sigma = 1.0f / sigp[0];
    const float w0 = cw[0], w1 = cw[1];

    float sqi[8], sqj[8];
#pragma unroll
    for (int u = 0; u < 8; ++u) {
        sqi[u] = sq[bN + i0 + ((u >> 2) << 6) + (ty << 2) + (u & 3)];
        sqj[u] = sq[bN + j0 + ((u >> 2) << 6) + (tx << 2) + (u & 3)];
    }

    auto cell = [&](float accv, float sqiv, float sqjv, float ainv, float amv) -> float {
        float d2 = sqiv + sqjv - 2.f * accv;
        d2 = fmaxf(d2, 0.f);
        const float ker = __expf(-d2 * inv_sigma);
        return (w0 * ainv + w1 * ker) * amv;
    };

#pragma unroll
    for (int u = 0; u < 8; ++u) {
        const int i = i0 + ((u >> 2) << 6) + (ty << 2) + (u & 3);
#pragma unroll
        for (int vh = 0; vh < 2; ++vh) {
            const size_t rbase = ((size_t)(bN + i) << 11) + j0 + (vh << 6) + (tx << 2);
            const float4 ain = *(const float4*)(adj_in + rbase);
            const float4 am  = *(const float4*)(adj_mask + rbase);
            float4 o;
            o.x = cell(acc[u][vh * 4 + 0], sqi[u], sqj[vh * 4 + 0], ain.x, am.x);
            o.y = cell(acc[u][vh * 4 + 1], sqi[u], sqj[vh * 4 + 1], ain.y, am.y);
            o.z = cell(acc[u][vh * 4 + 2], sqi[u], sqj[vh * 4 + 2], ain.z, am.z);
            o.w = cell(acc[u][vh * 4 + 3], sqi[u], sqj[vh * 4 + 3], ain.w, am.w);
            *(float4*)(adj_out + rbase) = o;
        }
    }
}

// ---------------------------------------------------------------------------
// Kernel 4: deg + op_adj (adj @ emb_n) + op_deg + conv matmul + nu matmul + relu.
// Block = 64 rows of one batch.  Thread (tx,ty): rows ty*4..+4, f = tx*4..+4.
// emb_n is recomputed on the fly from (mean,rstd,nb).  deg accumulated in the
// same j-loop.  Epilogue does the two 128x64 per-row matmuls from LDS.
// ---------------------------------------------------------------------------
__global__ __launch_bounds__(256) void k_agg(const float* __restrict__ adj,
                                             const float* __restrict__ emb,
                                             const float* __restrict__ meanp,
                                             const float* __restrict__ rstdp,
                                             const int* __restrict__ nbp,
                                             const float* __restrict__ convW,
                                             const float* __restrict__ convB,
                                             const float* __restrict__ nuW,
                                             const float* __restrict__ nuB,
                                             float* __restrict__ emb_out) {
    __shared__ __align__(16) float smem[13056];
    float* Adjs = smem;          // phase1: [64][68]  [j][i]
    float* Es   = smem + 4352;   // phase1: [64][68]  [j][f]
    float* xs   = smem;          // phase2: [64][132] [i][op_deg|op_adj]
    float* us   = smem + 8704;   // phase2/3: [64][68] emb_upd
    float* es   = smem;          // phase3: [64][68]  emb_in rows

    const int b   = blockIdx.y;
    const int i0  = blockIdx.x << 6;
    const int tid = threadIdx.x;
    const int tx = tid & 15, ty = tid >> 4;
    const int nb = nbp[b];
    const int bN = b * NN;
    const int sj  = tid >> 2;           // 0..63 (E/es staging row)
    const int scb = (tid & 3) << 4;     // 0,16,32,48
    const int air = tid & 63;           // Adjs staging row (i)
    const int ajc = (tid >> 6) << 4;    // Adjs staging col base (j)

    float4 mn4[4], rs4[4];
#pragma unroll
    for (int u = 0; u < 4; ++u) {
        mn4[u] = *(const float4*)(meanp + (b << 6) + scb + (u << 2));
        rs4[u] = *(const float4*)(rstdp + (b << 6) + scb + (u << 2));
    }

    float acc[4][4];
#pragma unroll
    for (int u = 0; u < 4; ++u)
#pragma unroll
        for (int v = 0; v < 4; ++v) acc[u][v] = 0.f;
    float dacc[4] = {0.f, 0.f, 0.f, 0.f};

    for (int jt = 0; jt < NN; jt += 64) {
        // stage adj tile (transposed -> [j][i])
#pragma unroll
        for (int u = 0; u < 16; u += 4) {
            const float4 v = *(const float4*)(adj + ((size_t)(bN + i0 + air) << 11) + jt + ajc + u);
            Adjs[(ajc + u + 0) * 68 + air] = v.x;
            Adjs[(ajc + u + 1) * 68 + air] = v.y;
            Adjs[(ajc + u + 2) * 68 + air] = v.z;
            Adjs[(ajc + u + 3) * 68 + air] = v.w;
        }
        // stage emb_n tile (on-the-fly layernorm)
        {
            const float msk = (jt + sj < nb) ? 1.f : 0.f;
            const float* pe = emb + ((size_t)(bN + jt + sj) << 6) + scb;
#pragma unroll
            for (int u = 0; u < 4; ++u) {
                const float4 v = *(const float4*)(pe + (u << 2));
                float4 o;
                o.x = (v.x - mn4[u].x) * rs4[u].x * msk;
                o.y = (v.y - mn4[u].y) * rs4[u].y * msk;
                o.z = (v.z - mn4[u].z) * rs4[u].z * msk;
                o.w = (v.w - mn4[u].w) * rs4[u].w * msk;
                *(float4*)&Es[sj * 68 + scb + (u << 2)] = o;
            }
        }
        __syncthreads();
#pragma unroll 8
        for (int j = 0; j < 64; ++j) {
            const float4 e = *(const float4*)&Es[j * 68 + (tx << 2)];
            const float4 a = *(const float4*)&Adjs[j * 68 + (ty << 2)];
            acc[0][0] = fmaf(a.x, e.x, acc[0][0]);
            acc[0][1] = fmaf(a.x, e.y, acc[0][1]);
            acc[0][2] = fmaf(a.x, e.z, acc[0][2]);
            acc[0][3] = fmaf(a.x, e.w, acc[0][3]);
            acc[1][0] = fmaf(a.y, e.x, acc[1][0]);
            acc[1][1] = fmaf(a.y, e.y, acc[1][1]);
            acc[1][2] = fmaf(a.y, e.z, acc[1][2]);
            acc[1][3] = fmaf(a.y, e.w, acc[1][3]);
            acc[2][0] = fmaf(a.z, e.x, acc[2][0]);
            acc[2][1] = fmaf(a.z, e.y, acc[2][1]);
            acc[2][2] = fmaf(a.z, e.z, acc[2][2]);
            acc[2][3] = fmaf(a.z, e.w, acc[2][3]);
            acc[3][0] = fmaf(a.w, e.x, acc[3][0]);
            acc[3][1] = fmaf(a.w, e.y, acc[3][1]);
            acc[3][2] = fmaf(a.w, e.z, acc[3][2]);
            acc[3][3] = fmaf(a.w, e.w, acc[3][3]);
            dacc[0] += a.x; dacc[1] += a.y; dacc[2] += a.z; dacc[3] += a.w;
        }
        __syncthreads();
    }

    // phase 2: xs[i][0:64] = op_deg = deg*emb_n ; xs[i][64:128] = op_adj
    {
        const float4 m4 = *(const float4*)(meanp + (b << 6) + (tx << 2));
        const float4 r4 = *(const float4*)(rstdp + (b << 6) + (tx << 2));
#pragma unroll
        for (int u = 0; u < 4; ++u) {
            const int il = (ty << 2) + u;
            const int gi = i0 + il;
            const float msk = (gi < nb) ? 1.f : 0.f;
            const float4 v = *(const float4*)(emb + ((size_t)(bN + gi) << 6) + (tx << 2));
            float4 en;
            en.x = (v.x - m4.x) * r4.x * msk;
            en.y = (v.y - m4.y) * r4.y * msk;
            en.z = (v.z - m4.z) * r4.z * msk;
            en.w = (v.w - m4.w) * r4.w * msk;
            float4 od;
            od.x = dacc[u] * en.x; od.y = dacc[u] * en.y;
            od.z = dacc[u] * en.z; od.w = dacc[u] * en.w;
            *(float4*)&xs[il * 132 + (tx << 2)] = od;
            float4 oa;
            oa.x = acc[u][0]; oa.y = acc[u][1]; oa.z = acc[u][2]; oa.w = acc[u][3];
            *(float4*)&xs[il * 132 + 64 + (tx << 2)] = oa;
        }
    }
    __syncthreads();

    // matmul 1: emb_upd = xs(64x128) @ convW(128x64) + convB  -> us
    {
        float u4[4][4];
#pragma unroll
        for (int r = 0; r < 4; ++r)
#pragma unroll
            for (int c = 0; c < 4; ++c) u4[r][c] = 0.f;
        for (int fis = 0; fis < 128; fis += 4) {
            const float4 w0v = *(const float4*)(convW + ((fis + 0) << 6) + (tx << 2));
            const float4 w1v = *(const float4*)(convW + ((fis + 1) << 6) + (tx << 2));
            const float4 w2v = *(const float4*)(convW + ((fis + 2) << 6) + (tx << 2));
            const float4 w3v = *(const float4*)(convW + ((fis + 3) << 6) + (tx << 2));
#pragma unroll
            for (int r = 0; r < 4; ++r) {
                const float4 x = *(const float4*)&xs[((ty << 2) + r) * 132 + fis];
                u4[r][0] += x.x * w0v.x + x.y * w1v.x + x.z * w2v.x + x.w * w3v.x;
                u4[r][1] += x.x * w0v.y + x.y * w1v.y + x.z * w2v.y + x.w * w3v.y;
                u4[r][2] += x.x * w0v.z + x.y * w1v.z + x.z * w2v.z + x.w * w3v.z;
                u4[r][3] += x.x * w0v.w + x.y * w1v.w + x.z * w2v.w + x.w * w3v.w;
            }
        }
        const float4 cb4 = *(const float4*)(convB + (tx << 2));
#pragma unroll
        for (int r = 0; r < 4; ++r) {
            float4 o;
            o.x = u4[r][0] + cb4.x; o.y = u4[r][1] + cb4.y;
            o.z = u4[r][2] + cb4.z; o.w = u4[r][3] + cb4.w;
            *(float4*)&us[((ty << 2) + r) * 68 + (tx << 2)] = o;
        }
    }
    __syncthreads();

    // stage emb_in rows for matmul 2 (reuses xs region)
    {
        const float* pe = emb + ((size_t)(bN + i0 + sj) << 6) + scb;
#pragma unroll
        for (int u = 0; u < 4; ++u)
            *(float4*)&es[sj * 68 + scb + (u << 2)] = *(const float4*)(pe + (u << 2));
    }
    __syncthreads();

    // matmul 2: emb = relu(concat(emb_in, emb_upd) @ nuW + nuB)
    {
        float u4[4][4];
#pragma unroll
        for (int r = 0; r < 4; ++r)
#pragma unroll
            for (int c = 0; c < 4; ++c) u4[r][c] = 0.f;
        for (int fis = 0; fis < 64; fis += 4) {
            const float4 w0v = *(const float4*)(nuW + ((fis + 0) << 6) + (tx << 2));
            const float4 w1v = *(const float4*)(nuW + ((fis + 1) << 6) + (tx << 2));
            const float4 w2v = *(const float4*)(nuW + ((fis + 2) << 6) + (tx << 2));
            const float4 w3v = *(const float4*)(nuW + ((fis + 3) << 6) + (tx << 2));
#pragma unroll
            for (int r = 0; r < 4; ++r) {
                const float4 x = *(const float4*)&es[((ty << 2) + r) * 68 + fis];
                u4[r][0] += x.x * w0v.x + x.y * w1v.x + x.z * w2v.x + x.w * w3v.x;
                u4[r][1] += x.x * w0v.y + x.y * w1v.y + x.z * w2v.y + x.w * w3v.y;
                u4[r][2] += x.x * w0v.z + x.y * w1v.z + x.z * w2v.z + x.w * w3v.z;
                u4[r][3] += x.x * w0v.w + x.y * w1v.w + x.z * w2v.w + x.w * w3v.w;
            }
        }
        for (int fis = 0; fis < 64; fis += 4) {
            const float4 w0v = *(const float4*)(nuW + ((64 + fis + 0) << 6) + (tx << 2));
            const float4 w1v = *(const float4*)(nuW + ((64 + fis + 1) << 6) + (tx << 2));
            const float4 w2v = *(const float4*)(nuW + ((64 + fis + 2) << 6) + (tx << 2));
            const float4 w3v = *(const float4*)(nuW + ((64 + fis + 3) << 6) + (tx << 2));
#pragma unroll
            for (int r = 0; r < 4; ++r) {
                const float4 x = *(const float4*)&us[((ty << 2) + r) * 68 + fis];
                u4[r][0] += x.x * w0v.x + x.y * w1v.x + x.z * w2v.x + x.w * w3v.x;
                u4[r][1] += x.x * w0v.y + x.y * w1v.y + x.z * w2v.y + x.w * w3v.y;
                u4[r][2] += x.x * w0v.z + x.y * w1v.z + x.z * w2v.z + x.w * w3v.z;
                u4[r][3] += x.x * w0v.w + x.y * w1v.w + x.z * w2v.w + x.w * w3v.w;
            }
        }
        const float4 nb4 = *(const float4*)(nuB + (tx << 2));
#pragma unroll
        for (int r = 0; r < 4; ++r) {
            const int gi = i0 + (ty << 2) + r;
            float4 o;
            o.x = fmaxf(u4[r][0] + nb4.x, 0.f);
            o.y = fmaxf(u4[r][1] + nb4.y, 0.f);
            o.z = fmaxf(u4[r][2] + nb4.z, 0.f);
            o.w = fmaxf(u4[r][3] + nb4.w, 0.f);
            *(float4*)(emb_out + ((size_t)(bN + gi) << 6) + (tx << 2)) = o;
        }
    }
}

// ---------------------------------------------------------------------------
extern "C" void kernel_launch(void* const* d_in, const int* in_sizes, int n_in,
                              void* d_out, int out_size, void* d_ws, size_t ws_size,
                              hipStream_t stream) {
    (void)in_sizes; (void)n_in; (void)out_size; (void)ws_size;
    const float* emb_in   = (const float*)d_in[0];
    const float* adj_in   = (const float*)d_in[1];
    const float* adj_mask = (const float*)d_in[2];
    const int*   nbp      = (const int*)d_in[3];
    const float* sigp     = (const float*)d_in[4];
    const float* cw       = (const float*)d_in[5];
    const float* convW    = (const float*)d_in[6];
    const float* convB    = (const float*)d_in[7];
    const float* nuW      = (const float*)d_in[8];
    const float* nuB      = (const float*)d_in[9];

    float* emb_out = (float*)d_out;
    float* adj_out = (float*)d_out + EMB_SZ;

    float* ws   = (float*)d_ws;
    float* sq   = ws + WS_SQ;
    float* asum = ws + WS_ASUM;
    float* asq  = ws + WS_ASQ;
    float* mean = ws + WS_MEAN;
    float* rstd = ws + WS_RSTD;

    // asum/asq are contiguous; ws is poisoned before every launch -> zero them.
    hipMemsetAsync(asum, 0, 2 * BB * FF * sizeof(float), stream);

    k_stats<<<dim3(16, BB), 256, 0, stream>>>(emb_in, sq, asum, asq);
    k_finalize<<<1, BB * FF, 0, stream>>>(asum, asq, nbp, mean, rstd);
    k_adj<<<dim3(NN / 128, NN / 128, BB), 256, 0, stream>>>(emb_in, adj_in, adj_mask,
                                                            sq, sigp, cw, adj_out);
    k_agg<<<dim3(NN / 64, BB), 256, 0, stream>>>(adj_out, emb_in, mean, rstd, nbp,
                                                 convW, convB, nuW, nuB, emb_out);
}

// Round 2
// 432.054 us; speedup vs baseline: 1.1787x; 1.1787x over previous
//
#include <hip/hip_runtime.h>
#include <math.h>

#define BB 8
#define NN 2048
#define FF 64
#define EPSV 1e-5f
#define EMB_SZ (BB * NN * FF)

// workspace layout (floats)
#define WS_SQ    0                     // BB*NN
#define WS_ASUM  (BB * NN)             // 16384  (BB*FF)
#define WS_ASQ   (WS_ASUM + BB * FF)   // 16896
#define WS_MEAN  (WS_ASQ + BB * FF)    // 17408
#define WS_RSTD  (WS_MEAN + BB * FF)   // 17920
#define WS_DEG   (WS_RSTD + BB * FF)   // 18432  (BB*NN)

// ---------------------------------------------------------------------------
// Kernel 1: per-row squared norm (sq) + per-(b,f) partial sums for mean/var.
// emb_in is pre-masked (rows >= nb are zero), so unmasked sums == masked sums.
// ---------------------------------------------------------------------------
__global__ __launch_bounds__(256) void k_stats(const float* __restrict__ emb,
                                               float* __restrict__ sq,
                                               float* __restrict__ asum,
                                               float* __restrict__ asq) {
    const int b    = blockIdx.y;
    const int lane = threadIdx.x & 63;
    const int grp  = threadIdx.x >> 6;
    const int base_i = blockIdx.x << 7;

    float s = 0.f, q = 0.f;
    for (int it = 0; it < 32; ++it) {
        const int i = base_i + (it << 2) + grp;
        const float x = emb[((size_t)(b * NN + i) << 6) + lane];
        const float x2 = x * x;
        s += x;
        q += x2;
        float r = x2;  // row reduction across the 64-lane group
        r += __shfl_xor(r, 1);
        r += __shfl_xor(r, 2);
        r += __shfl_xor(r, 4);
        r += __shfl_xor(r, 8);
        r += __shfl_xor(r, 16);
        r += __shfl_xor(r, 32);
        if (lane == 0) sq[b * NN + i] = r;
    }
    __shared__ float redS[4][64];
    __shared__ float redQ[4][64];
    redS[grp][lane] = s;
    redQ[grp][lane] = q;
    __syncthreads();
    if (threadIdx.x < 64) {
        const float ts = redS[0][lane] + redS[1][lane] + redS[2][lane] + redS[3][lane];
        const float tq = redQ[0][lane] + redQ[1][lane] + redQ[2][lane] + redQ[3][lane];
        atomicAdd(&asum[(b << 6) + lane], ts);
        atomicAdd(&asq[(b << 6) + lane], tq);
    }
}

// ---------------------------------------------------------------------------
// Kernel 2: finalize mean / rstd.  1 block, 512 threads (= B*F).
// ---------------------------------------------------------------------------
__global__ void k_finalize(const float* __restrict__ asum, const float* __restrict__ asq,
                           const int* __restrict__ nbp,
                           float* __restrict__ mean, float* __restrict__ rstd) {
    const int t = threadIdx.x;       // 0..511
    const int b = t >> 6;
    const float cnt = fmaxf((float)nbp[b], 1.f);
    const float m = asum[t] / cnt;
    float v = asq[t] / cnt - m * m;
    v = fmaxf(v, 0.f);
    mean[t] = m;
    rstd[t] = rsqrtf(v + EPSV);
}

// ---------------------------------------------------------------------------
// Kernel 3: adj = (w0*adj_in + w1*exp(-max(d2,0)/sigma)) * mask, mask computed
// from nb (no adj_mask reads).  Dead tiles (i0>=nb || j0>=nb) write zeros and
// skip all loads/compute (~42% of tiles).  Also accumulates deg[i] = sum_j adj
// via register rowsums + shfl_xor reduce + one atomic per 16 lanes.
// 128x128 tile per block, K=64 in two 32-slices.
// ---------------------------------------------------------------------------
__global__ __launch_bounds__(256) void k_adj_deg(const float* __restrict__ emb,
                                                 const float* __restrict__ adj_in,
                                                 const float* __restrict__ sq,
                                                 const float* __restrict__ sigp,
                                                 const float* __restrict__ cw,
                                                 const int* __restrict__ nbp,
                                                 float* __restrict__ adj_out,
                                                 float* __restrict__ deg) {
    __shared__ __align__(16) float As[32][132];  // [k][i]
    __shared__ __align__(16) float Bs[32][132];  // [k][j]
    const int b  = blockIdx.z;
    const int i0 = blockIdx.y << 7;
    const int j0 = blockIdx.x << 7;
    const int tid = threadIdx.x;
    const int tx = tid & 15, ty = tid >> 4;
    const int nb = nbp[b];
    const int bN = b * NN;

    if (i0 >= nb || j0 >= nb) {
        // dead tile: adj = 0 everywhere here
        const float4 z4 = make_float4(0.f, 0.f, 0.f, 0.f);
#pragma unroll
        for (int u = 0; u < 8; ++u) {
            const int i = i0 + ((u >> 2) << 6) + (ty << 2) + (u & 3);
#pragma unroll
            for (int vh = 0; vh < 2; ++vh) {
                const size_t rbase = ((size_t)(bN + i) << 11) + j0 + (vh << 6) + (tx << 2);
                *(float4*)(adj_out + rbase) = z4;
            }
        }
        return;
    }

    const int srow = tid & 31;
    const int scb  = (tid >> 5) << 2;  // 0,4,...,28

    float acc[8][8];
#pragma unroll
    for (int u = 0; u < 8; ++u)
#pragma unroll
        for (int v = 0; v < 8; ++v) acc[u][v] = 0.f;

    for (int kt = 0; kt < FF; kt += 32) {
#pragma unroll
        for (int p = 0; p < 4; ++p) {
            const int row = srow + (p << 5);  // 0..127
            const float4 a  = *(const float4*)(emb + ((size_t)(bN + i0 + row) << 6) + kt + scb);
            const float4 bb = *(const float4*)(emb + ((size_t)(bN + j0 + row) << 6) + kt + scb);
            As[scb + 0][row] = a.x;  As[scb + 1][row] = a.y;
            As[scb + 2][row] = a.z;  As[scb + 3][row] = a.w;
            Bs[scb + 0][row] = bb.x; Bs[scb + 1][row] = bb.y;
            Bs[scb + 2][row] = bb.z; Bs[scb + 3][row] = bb.w;
        }
        __syncthreads();
#pragma unroll 4
        for (int k = 0; k < 32; ++k) {
            const float4 a0 = *(const float4*)&As[k][(ty << 2)];
            const float4 a1 = *(const float4*)&As[k][64 + (ty << 2)];
            const float4 b0 = *(const float4*)&Bs[k][(tx << 2)];
            const float4 b1 = *(const float4*)&Bs[k][64 + (tx << 2)];
            const float av[8] = {a0.x, a0.y, a0.z, a0.w, a1.x, a1.y, a1.z, a1.w};
            const float bv[8] = {b0.x, b0.y, b0.z, b0.w, b1.x, b1.y, b1.z, b1.w};
#pragma unroll
            for (int u = 0; u < 8; ++u)
#pragma unroll
                for (int v = 0; v < 8; ++v)
                    acc[u][v] = fmaf(av[u], bv[v], acc[u][v]);
        }
        __syncthreads();
    }

    const float inv_sigma = 1.0f / sigp[0];
    const float w0 = cw[0], w1 = cw[1];

    float sqi[8], sqj[8];
#pragma unroll
    for (int u = 0; u < 8; ++u) {
        sqi[u] = sq[bN + i0 + ((u >> 2) << 6) + (ty << 2) + (u & 3)];
        sqj[u] = sq[bN + j0 + ((u >> 2) << 6) + (tx << 2) + (u & 3)];
    }

    auto cell = [&](float accv, float sqiv, float sqjv, float ainv, float amv) -> float {
        float d2 = sqiv + sqjv - 2.f * accv;
        d2 = fmaxf(d2, 0.f);
        const float ker = __expf(-d2 * inv_sigma);
        return (w0 * ainv + w1 * ker) * amv;
    };

    float rs8[8];
#pragma unroll
    for (int u = 0; u < 8; ++u) {
        const int i = i0 + ((u >> 2) << 6) + (ty << 2) + (u & 3);
        const float mi = (i < nb) ? 1.f : 0.f;
        float rsum = 0.f;
#pragma unroll
        for (int vh = 0; vh < 2; ++vh) {
            const int jb = j0 + (vh << 6) + (tx << 2);
            const size_t rbase = ((size_t)(bN + i) << 11) + jb;
            const float4 ain = *(const float4*)(adj_in + rbase);
            float4 o;
            o.x = cell(acc[u][vh * 4 + 0], sqi[u], sqj[vh * 4 + 0], ain.x,
                       (jb + 0 < nb) ? mi : 0.f);
            o.y = cell(acc[u][vh * 4 + 1], sqi[u], sqj[vh * 4 + 1], ain.y,
                       (jb + 1 < nb) ? mi : 0.f);
            o.z = cell(acc[u][vh * 4 + 2], sqi[u], sqj[vh * 4 + 2], ain.z,
                       (jb + 2 < nb) ? mi : 0.f);
            o.w = cell(acc[u][vh * 4 + 3], sqi[u], sqj[vh * 4 + 3], ain.w,
                       (jb + 3 < nb) ? mi : 0.f);
            *(float4*)(adj_out + rbase) = o;
            rsum += o.x + o.y + o.z + o.w;
        }
        rs8[u] = rsum;
    }
    // deg: reduce rowsums across tx (16 lanes), one atomic per row
#pragma unroll
    for (int u = 0; u < 8; ++u) {
        float v = rs8[u];
        v += __shfl_xor(v, 1);
        v += __shfl_xor(v, 2);
        v += __shfl_xor(v, 4);
        v += __shfl_xor(v, 8);
        if (tx == 0) {
            const int i = i0 + ((u >> 2) << 6) + (ty << 2) + (u & 3);
            atomicAdd(&deg[bN + i], v);
        }
    }
}

// ---------------------------------------------------------------------------
// Kernel 4: op_adj partials.  Grid (32 i-tiles, 4 j-chunks, 8 b); each block
// does 64 rows x 512 j-cols, skipping i0>=nb / j>=nb.  Accumulates via
// atomicAdd into the emb region of d_out (pre-zeroed).
// ---------------------------------------------------------------------------
__global__ __launch_bounds__(256) void k_aggpart(const float* __restrict__ adj,
                                                 const float* __restrict__ emb,
                                                 const float* __restrict__ meanp,
                                                 const float* __restrict__ rstdp,
                                                 const int* __restrict__ nbp,
                                                 float* __restrict__ opadj) {
    __shared__ __align__(16) float Adjs[64 * 68];  // [j][i]
    __shared__ __align__(16) float Es[64 * 68];    // [j][f]
    const int b  = blockIdx.z;
    const int i0 = blockIdx.x << 6;
    const int nb = nbp[b];
    if (i0 >= nb) return;
    const int jbeg = blockIdx.y << 9;
    if (jbeg >= nb) return;
    const int jend = min(jbeg + 512, (nb + 63) & ~63);

    const int tid = threadIdx.x;
    const int tx = tid & 15, ty = tid >> 4;
    const int bN = b * NN;
    const int sj  = tid >> 2;           // 0..63
    const int scb = (tid & 3) << 4;     // 0,16,32,48
    const int air = tid & 63;
    const int ajc = (tid >> 6) << 4;

    float4 mn4[4], rs4[4];
#pragma unroll
    for (int u = 0; u < 4; ++u) {
        mn4[u] = *(const float4*)(meanp + (b << 6) + scb + (u << 2));
        rs4[u] = *(const float4*)(rstdp + (b << 6) + scb + (u << 2));
    }

    float acc[4][4];
#pragma unroll
    for (int u = 0; u < 4; ++u)
#pragma unroll
        for (int v = 0; v < 4; ++v) acc[u][v] = 0.f;

    for (int jt = jbeg; jt < jend; jt += 64) {
#pragma unroll
        for (int u = 0; u < 16; u += 4) {
            const float4 v = *(const float4*)(adj + ((size_t)(bN + i0 + air) << 11) + jt + ajc + u);
            Adjs[(ajc + u + 0) * 68 + air] = v.x;
            Adjs[(ajc + u + 1) * 68 + air] = v.y;
            Adjs[(ajc + u + 2) * 68 + air] = v.z;
            Adjs[(ajc + u + 3) * 68 + air] = v.w;
        }
        {
            const float msk = (jt + sj < nb) ? 1.f : 0.f;
            const float* pe = emb + ((size_t)(bN + jt + sj) << 6) + scb;
#pragma unroll
            for (int u = 0; u < 4; ++u) {
                const float4 v = *(const float4*)(pe + (u << 2));
                float4 o;
                o.x = (v.x - mn4[u].x) * rs4[u].x * msk;
                o.y = (v.y - mn4[u].y) * rs4[u].y * msk;
                o.z = (v.z - mn4[u].z) * rs4[u].z * msk;
                o.w = (v.w - mn4[u].w) * rs4[u].w * msk;
                *(float4*)&Es[sj * 68 + scb + (u << 2)] = o;
            }
        }
        __syncthreads();
#pragma unroll 8
        for (int j = 0; j < 64; ++j) {
            const float4 e = *(const float4*)&Es[j * 68 + (tx << 2)];
            const float4 a = *(const float4*)&Adjs[j * 68 + (ty << 2)];
            acc[0][0] = fmaf(a.x, e.x, acc[0][0]);
            acc[0][1] = fmaf(a.x, e.y, acc[0][1]);
            acc[0][2] = fmaf(a.x, e.z, acc[0][2]);
            acc[0][3] = fmaf(a.x, e.w, acc[0][3]);
            acc[1][0] = fmaf(a.y, e.x, acc[1][0]);
            acc[1][1] = fmaf(a.y, e.y, acc[1][1]);
            acc[1][2] = fmaf(a.y, e.z, acc[1][2]);
            acc[1][3] = fmaf(a.y, e.w, acc[1][3]);
            acc[2][0] = fmaf(a.z, e.x, acc[2][0]);
            acc[2][1] = fmaf(a.z, e.y, acc[2][1]);
            acc[2][2] = fmaf(a.z, e.z, acc[2][2]);
            acc[2][3] = fmaf(a.z, e.w, acc[2][3]);
            acc[3][0] = fmaf(a.w, e.x, acc[3][0]);
            acc[3][1] = fmaf(a.w, e.y, acc[3][1]);
            acc[3][2] = fmaf(a.w, e.z, acc[3][2]);
            acc[3][3] = fmaf(a.w, e.w, acc[3][3]);
        }
        __syncthreads();
    }

#pragma unroll
    for (int u = 0; u < 4; ++u) {
        const int gi = i0 + (ty << 2) + u;
        float* p = opadj + (((size_t)(bN + gi)) << 6) + (tx << 2);
        atomicAdd(p + 0, acc[u][0]);
        atomicAdd(p + 1, acc[u][1]);
        atomicAdd(p + 2, acc[u][2]);
        atomicAdd(p + 3, acc[u][3]);
    }
}

// ---------------------------------------------------------------------------
// Kernel 5: epilogue.  Reads op_adj (from emb region of d_out) + deg, builds
// [op_deg | op_adj], conv matmul, nu matmul, relu; overwrites emb_out rows.
// ---------------------------------------------------------------------------
__global__ __launch_bounds__(256) void k_epilogue(const float* __restrict__ emb,
                                                  const float* __restrict__ meanp,
                                                  const float* __restrict__ rstdp,
                                                  const float* __restrict__ degp,
                                                  const int* __restrict__ nbp,
                                                  const float* __restrict__ convW,
                                                  const float* __restrict__ convB,
                                                  const float* __restrict__ nuW,
                                                  const float* __restrict__ nuB,
                                                  float* __restrict__ emb_out) {
    __shared__ __align__(16) float smem[13056];
    float* xs = smem;          // [64][132] [i][op_deg|op_adj]
    float* us = smem + 8704;   // [64][68] emb_upd
    float* es = smem;          // reuse: [64][68] emb_in rows

    const int b   = blockIdx.y;
    const int i0  = blockIdx.x << 6;
    const int tid = threadIdx.x;
    const int tx = tid & 15, ty = tid >> 4;
    const int nb = nbp[b];
    const int bN = b * NN;
    const int sj  = tid >> 2;
    const int scb = (tid & 3) << 4;

    // phase 1: xs = [op_deg | op_adj]
    {
        const float4 m4 = *(const float4*)(meanp + (b << 6) + (tx << 2));
        const float4 r4 = *(const float4*)(rstdp + (b << 6) + (tx << 2));
#pragma unroll
        for (int u = 0; u < 4; ++u) {
            const int il = (ty << 2) + u;
            const int gi = i0 + il;
            const float msk = (gi < nb) ? 1.f : 0.f;
            const float dg = degp[bN + gi];
            const float4 v = *(const float4*)(emb + ((size_t)(bN + gi) << 6) + (tx << 2));
            float4 en;
            en.x = (v.x - m4.x) * r4.x * msk;
            en.y = (v.y - m4.y) * r4.y * msk;
            en.z = (v.z - m4.z) * r4.z * msk;
            en.w = (v.w - m4.w) * r4.w * msk;
            float4 od;
            od.x = dg * en.x; od.y = dg * en.y; od.z = dg * en.z; od.w = dg * en.w;
            *(float4*)&xs[il * 132 + (tx << 2)] = od;
            const float4 oa = *(const float4*)(emb_out + ((size_t)(bN + gi) << 6) + (tx << 2));
            *(float4*)&xs[il * 132 + 64 + (tx << 2)] = oa;
        }
    }
    __syncthreads();

    // matmul 1: emb_upd = xs(64x128) @ convW(128x64) + convB -> us
    {
        float u4[4][4];
#pragma unroll
        for (int r = 0; r < 4; ++r)
#pragma unroll
            for (int c = 0; c < 4; ++c) u4[r][c] = 0.f;
        for (int fis = 0; fis < 128; fis += 4) {
            const float4 w0v = *(const float4*)(convW + ((fis + 0) << 6) + (tx << 2));
            const float4 w1v = *(const float4*)(convW + ((fis + 1) << 6) + (tx << 2));
            const float4 w2v = *(const float4*)(convW + ((fis + 2) << 6) + (tx << 2));
            const float4 w3v = *(const float4*)(convW + ((fis + 3) << 6) + (tx << 2));
#pragma unroll
            for (int r = 0; r < 4; ++r) {
                const float4 x = *(const float4*)&xs[((ty << 2) + r) * 132 + fis];
                u4[r][0] += x.x * w0v.x + x.y * w1v.x + x.z * w2v.x + x.w * w3v.x;
                u4[r][1] += x.x * w0v.y + x.y * w1v.y + x.z * w2v.y + x.w * w3v.y;
                u4[r][2] += x.x * w0v.z + x.y * w1v.z + x.z * w2v.z + x.w * w3v.z;
                u4[r][3] += x.x * w0v.w + x.y * w1v.w + x.z * w2v.w + x.w * w3v.w;
            }
        }
        const float4 cb4 = *(const float4*)(convB + (tx << 2));
#pragma unroll
        for (int r = 0; r < 4; ++r) {
            float4 o;
            o.x = u4[r][0] + cb4.x; o.y = u4[r][1] + cb4.y;
            o.z = u4[r][2] + cb4.z; o.w = u4[r][3] + cb4.w;
            *(float4*)&us[((ty << 2) + r) * 68 + (tx << 2)] = o;
        }
    }
    __syncthreads();

    // stage emb_in rows (reuses xs region)
    {
        const float* pe = emb + ((size_t)(bN + i0 + sj) << 6) + scb;
#pragma unroll
        for (int u = 0; u < 4; ++u)
            *(float4*)&es[sj * 68 + scb + (u << 2)] = *(const float4*)(pe + (u << 2));
    }
    __syncthreads();

    // matmul 2: emb = relu(concat(emb_in, emb_upd) @ nuW + nuB)
    {
        float u4[4][4];
#pragma unroll
        for (int r = 0; r < 4; ++r)
#pragma unroll
            for (int c = 0; c < 4; ++c) u4[r][c] = 0.f;
        for (int fis = 0; fis < 64; fis += 4) {
            const float4 w0v = *(const float4*)(nuW + ((fis + 0) << 6) + (tx << 2));
            const float4 w1v = *(const float4*)(nuW + ((fis + 1) << 6) + (tx << 2));
            const float4 w2v = *(const float4*)(nuW + ((fis + 2) << 6) + (tx << 2));
            const float4 w3v = *(const float4*)(nuW + ((fis + 3) << 6) + (tx << 2));
#pragma unroll
            for (int r = 0; r < 4; ++r) {
                const float4 x = *(const float4*)&es[((ty << 2) + r) * 68 + fis];
                u4[r][0] += x.x * w0v.x + x.y * w1v.x + x.z * w2v.x + x.w * w3v.x;
                u4[r][1] += x.x * w0v.y + x.y * w1v.y + x.z * w2v.y + x.w * w3v.y;
                u4[r][2] += x.x * w0v.z + x.y * w1v.z + x.z * w2v.z + x.w * w3v.z;
                u4[r][3] += x.x * w0v.w + x.y * w1v.w + x.z * w2v.w + x.w * w3v.w;
            }
        }
        for (int fis = 0; fis < 64; fis += 4) {
            const float4 w0v = *(const float4*)(nuW + ((64 + fis + 0) << 6) + (tx << 2));
            const float4 w1v = *(const float4*)(nuW + ((64 + fis + 1) << 6) + (tx << 2));
            const float4 w2v = *(const float4*)(nuW + ((64 + fis + 2) << 6) + (tx << 2));
            const float4 w3v = *(const float4*)(nuW + ((64 + fis + 3) << 6) + (tx << 2));
#pragma unroll
            for (int r = 0; r < 4; ++r) {
                const float4 x = *(const float4*)&us[((ty << 2) + r) * 68 + fis];
                u4[r][0] += x.x * w0v.x + x.y * w1v.x + x.z * w2v.x + x.w * w3v.x;
                u4[r][1] += x.x * w0v.y + x.y * w1v.y + x.z * w2v.y + x.w * w3v.y;
                u4[r][2] += x.x * w0v.z + x.y * w1v.z + x.z * w2v.z + x.w * w3v.z;
                u4[r][3] += x.x * w0v.w + x.y * w1v.w + x.z * w2v.w + x.w * w3v.w;
            }
        }
        const float4 nb4 = *(const float4*)(nuB + (tx << 2));
#pragma unroll
        for (int r = 0; r < 4; ++r) {
            const int gi = i0 + (ty << 2) + r;
            float4 o;
            o.x = fmaxf(u4[r][0] + nb4.x, 0.f);
            o.y = fmaxf(u4[r][1] + nb4.y, 0.f);
            o.z = fmaxf(u4[r][2] + nb4.z, 0.f);
            o.w = fmaxf(u4[r][3] + nb4.w, 0.f);
            *(float4*)(emb_out + ((size_t)(bN + gi) << 6) + (tx << 2)) = o;
        }
    }
}

// ---------------------------------------------------------------------------
extern "C" void kernel_launch(void* const* d_in, const int* in_sizes, int n_in,
                              void* d_out, int out_size, void* d_ws, size_t ws_size,
                              hipStream_t stream) {
    (void)in_sizes; (void)n_in; (void)out_size; (void)ws_size;
    const float* emb_in   = (const float*)d_in[0];
    const float* adj_in   = (const float*)d_in[1];
    const int*   nbp      = (const int*)d_in[3];
    const float* sigp     = (const float*)d_in[4];
    const float* cw       = (const float*)d_in[5];
    const float* convW    = (const float*)d_in[6];
    const float* convB    = (const float*)d_in[7];
    const float* nuW      = (const float*)d_in[8];
    const float* nuB      = (const float*)d_in[9];

    float* emb_out = (float*)d_out;
    float* adj_out = (float*)d_out + EMB_SZ;

    float* ws   = (float*)d_ws;
    float* sq   = ws + WS_SQ;
    float* asum = ws + WS_ASUM;
    float* asq  = ws + WS_ASQ;
    float* mean = ws + WS_MEAN;
    float* rstd = ws + WS_RSTD;
    float* deg  = ws + WS_DEG;

    // zero accumulators (ws/d_out are poisoned before every launch)
    hipMemsetAsync(asum, 0, 2 * BB * FF * sizeof(float), stream);
    hipMemsetAsync(deg, 0, BB * NN * sizeof(float), stream);
    hipMemsetAsync(emb_out, 0, (size_t)EMB_SZ * sizeof(float), stream);

    k_stats<<<dim3(16, BB), 256, 0, stream>>>(emb_in, sq, asum, asq);
    k_finalize<<<1, BB * FF, 0, stream>>>(asum, asq, nbp, mean, rstd);
    k_adj_deg<<<dim3(NN / 128, NN / 128, BB), 256, 0, stream>>>(emb_in, adj_in, sq, sigp,
                                                                cw, nbp, adj_out, deg);
    k_aggpart<<<dim3(NN / 64, 4, BB), 256, 0, stream>>>(adj_out, emb_in, mean, rstd,
                                                        nbp, emb_out);
    k_epilogue<<<dim3(NN / 64, BB), 256, 0, stream>>>(emb_in, mean, rstd, deg, nbp,
                                                      convW, convB, nuW, nuB, emb_out);
}

// Round 3
// 395.165 us; speedup vs baseline: 1.2887x; 1.0934x over previous
//
#include <hip/hip_runtime.h>
#include <math.h>

#define BB 8
#define NN 2048
#define FF 64
#define EPSV 1e-5f
#define EMB_SZ (BB * NN * FF)

// workspace layout (floats)
#define WS_SQ    0                     // BB*NN
#define WS_ASUM  (BB * NN)             // 16384  (BB*FF)
#define WS_ASQ   (WS_ASUM + BB * FF)   // 16896
#define WS_MEAN  (WS_ASQ + BB * FF)    // 17408
#define WS_RSTD  (WS_MEAN + BB * FF)   // 17920
#define WS_DEG   (WS_RSTD + BB * FF)   // 18432  (BB*NN)

typedef __attribute__((ext_vector_type(8))) short bf16x8;
typedef __attribute__((ext_vector_type(4))) float f32x4;

__device__ inline unsigned short f2bf(float x) {
    union { float f; unsigned u; } v; v.f = x;
    return (unsigned short)((v.u + 0x7fffu + ((v.u >> 16) & 1u)) >> 16);
}
__device__ inline float bf2f(unsigned short h) {
    union { float f; unsigned u; } v; v.u = ((unsigned)h) << 16;
    return v.f;
}

// ---------------------------------------------------------------------------
// Kernel 1: per-row squared norm (sq) + per-(b,f) partial sums for mean/var.
// grid (32, B): 64 rows/block.  emb_in pre-masked -> unmasked sums are exact.
// ---------------------------------------------------------------------------
__global__ __launch_bounds__(256) void k_stats(const float* __restrict__ emb,
                                               float* __restrict__ sq,
                                               float* __restrict__ asum,
                                               float* __restrict__ asq) {
    const int b    = blockIdx.y;
    const int lane = threadIdx.x & 63;
    const int grp  = threadIdx.x >> 6;
    const int base_i = blockIdx.x << 6;

    float s = 0.f, q = 0.f;
    for (int it = 0; it < 16; ++it) {
        const int i = base_i + (it << 2) + grp;
        const float x = emb[((size_t)(b * NN + i) << 6) + lane];
        const float x2 = x * x;
        s += x;
        q += x2;
        float r = x2;
        r += __shfl_xor(r, 1);
        r += __shfl_xor(r, 2);
        r += __shfl_xor(r, 4);
        r += __shfl_xor(r, 8);
        r += __shfl_xor(r, 16);
        r += __shfl_xor(r, 32);
        if (lane == 0) sq[b * NN + i] = r;
    }
    __shared__ float redS[4][64];
    __shared__ float redQ[4][64];
    redS[grp][lane] = s;
    redQ[grp][lane] = q;
    __syncthreads();
    if (threadIdx.x < 64) {
        const float ts = redS[0][lane] + redS[1][lane] + redS[2][lane] + redS[3][lane];
        const float tq = redQ[0][lane] + redQ[1][lane] + redQ[2][lane] + redQ[3][lane];
        atomicAdd(&asum[(b << 6) + lane], ts);
        atomicAdd(&asq[(b << 6) + lane], tq);
    }
}

// ---------------------------------------------------------------------------
// Kernel 2: finalize mean / rstd.  1 block, 512 threads (= B*F).
// ---------------------------------------------------------------------------
__global__ void k_finalize(const float* __restrict__ asum, const float* __restrict__ asq,
                           const int* __restrict__ nbp,
                           float* __restrict__ mean, float* __restrict__ rstd) {
    const int t = threadIdx.x;
    const int b = t >> 6;
    const float cnt = fmaxf((float)nbp[b], 1.f);
    const float m = asum[t] / cnt;
    float v = asq[t] / cnt - m * m;
    v = fmaxf(v, 0.f);
    mean[t] = m;
    rstd[t] = rsqrtf(v + EPSV);
}

// ---------------------------------------------------------------------------
// Kernel 3: adj + deg via bf16x2-split MFMA Gram (hh+hl+lh: ~fp32 precision).
// Block tile 64(i) x 128(j), 4 waves; wave w owns C rows w*16..+16, all 128 j.
// LDS: emb hi/lo tiles, row-major [row][k] padded to 40 bf16 (80B stride ->
// <=2-way bank aliasing on ds_read_b128).  K=64 staged in two 32-halves.
// gemm_bt pattern: both frags from row-major LDS; C: col=lane&15,
// row=(lane>>4)*4+reg  [m89-verified mapping].
// ---------------------------------------------------------------------------
__global__ __launch_bounds__(256, 4) void k_adj_deg(const float* __restrict__ emb,
                                                    const float* __restrict__ adj_in,
                                                    const float* __restrict__ sq,
                                                    const float* __restrict__ sigp,
                                                    const float* __restrict__ cw,
                                                    const int* __restrict__ nbp,
                                                    float* __restrict__ adj_out,
                                                    float* __restrict__ deg) {
    __shared__ __align__(16) unsigned short Ah[64][40];
    __shared__ __align__(16) unsigned short Al[64][40];
    __shared__ __align__(16) unsigned short Bh[128][40];
    __shared__ __align__(16) unsigned short Bl[128][40];

    const int b  = blockIdx.z;
    const int j0 = blockIdx.x << 7;   // 16 j-tiles
    const int i0 = blockIdx.y << 6;   // 32 i-tiles
    const int nb = nbp[b];
    const int bN = b * NN;
    const int tid = threadIdx.x;

    if (i0 >= nb || j0 >= nb) {
        const float4 z = make_float4(0.f, 0.f, 0.f, 0.f);
#pragma unroll
        for (int qq = 0; qq < 8; ++qq) {
            const int idx = tid * 8 + qq;          // 0..2047 float4s
            const int row = idx >> 5, c4 = (idx & 31) << 2;
            *(float4*)(adj_out + ((size_t)(bN + i0 + row) << 11) + j0 + c4) = z;
        }
        return;
    }

    const int w   = tid >> 6;
    const int lane = tid & 63;
    const int l15 = lane & 15, lq = lane >> 4;

    f32x4 acc[8];
#pragma unroll
    for (int c = 0; c < 8; ++c) acc[c] = (f32x4){0.f, 0.f, 0.f, 0.f};

    for (int kh = 0; kh < 64; kh += 32) {
        // stage B (128 rows x 32 k): all threads; row = t>>1, kc = (t&1)*16
        {
            const int row = tid >> 1, kc = (tid & 1) << 4;
            const float* src = emb + ((size_t)(bN + j0 + row) << 6) + kh + kc;
            __align__(16) float xv[16];
            *(float4*)(xv + 0)  = *(const float4*)(src + 0);
            *(float4*)(xv + 4)  = *(const float4*)(src + 4);
            *(float4*)(xv + 8)  = *(const float4*)(src + 8);
            *(float4*)(xv + 12) = *(const float4*)(src + 12);
            __align__(16) unsigned short hh[16], ll[16];
#pragma unroll
            for (int e = 0; e < 16; ++e) {
                hh[e] = f2bf(xv[e]);
                ll[e] = f2bf(xv[e] - bf2f(hh[e]));
            }
            *(bf16x8*)&Bh[row][kc]     = *(bf16x8*)&hh[0];
            *(bf16x8*)&Bh[row][kc + 8] = *(bf16x8*)&hh[8];
            *(bf16x8*)&Bl[row][kc]     = *(bf16x8*)&ll[0];
            *(bf16x8*)&Bl[row][kc + 8] = *(bf16x8*)&ll[8];
        }
        // stage A (64 rows x 32 k): threads < 128
        if (tid < 128) {
            const int row = tid >> 1, kc = (tid & 1) << 4;
            const float* src = emb + ((size_t)(bN + i0 + row) << 6) + kh + kc;
            __align__(16) float xv[16];
            *(float4*)(xv + 0)  = *(const float4*)(src + 0);
            *(float4*)(xv + 4)  = *(const float4*)(src + 4);
            *(float4*)(xv + 8)  = *(const float4*)(src + 8);
            *(float4*)(xv + 12) = *(const float4*)(src + 12);
            __align__(16) unsigned short hh[16], ll[16];
#pragma unroll
            for (int e = 0; e < 16; ++e) {
                hh[e] = f2bf(xv[e]);
                ll[e] = f2bf(xv[e] - bf2f(hh[e]));
            }
            *(bf16x8*)&Ah[row][kc]     = *(bf16x8*)&hh[0];
            *(bf16x8*)&Ah[row][kc + 8] = *(bf16x8*)&hh[8];
            *(bf16x8*)&Al[row][kc]     = *(bf16x8*)&ll[0];
            *(bf16x8*)&Al[row][kc + 8] = *(bf16x8*)&ll[8];
        }
        __syncthreads();

        const bf16x8 ah = *(bf16x8*)&Ah[w * 16 + l15][lq * 8];
        const bf16x8 al = *(bf16x8*)&Al[w * 16 + l15][lq * 8];
#pragma unroll
        for (int c = 0; c < 8; ++c) {
            const bf16x8 bh = *(bf16x8*)&Bh[c * 16 + l15][lq * 8];
            const bf16x8 bl = *(bf16x8*)&Bl[c * 16 + l15][lq * 8];
            acc[c] = __builtin_amdgcn_mfma_f32_16x16x32_bf16(ah, bh, acc[c], 0, 0, 0);
            acc[c] = __builtin_amdgcn_mfma_f32_16x16x32_bf16(ah, bl, acc[c], 0, 0, 0);
            acc[c] = __builtin_amdgcn_mfma_f32_16x16x32_bf16(al, bh, acc[c], 0, 0, 0);
        }
        __syncthreads();
    }

    const float inv_sigma = 1.0f / sigp[0];
    const float w0 = cw[0], w1 = cw[1];

    float sqi[4], sqj[8];
    const int irow0 = i0 + w * 16 + lq * 4;
#pragma unroll
    for (int r = 0; r < 4; ++r) sqi[r] = sq[bN + irow0 + r];
#pragma unroll
    for (int c = 0; c < 8; ++c) sqj[c] = sq[bN + j0 + c * 16 + l15];

#pragma unroll
    for (int r = 0; r < 4; ++r) {
        const int gi = irow0 + r;
        const float mi = (gi < nb) ? 1.f : 0.f;
        float ain[8];
#pragma unroll
        for (int c = 0; c < 8; ++c)
            ain[c] = adj_in[((size_t)(bN + gi) << 11) + j0 + c * 16 + l15];
        float rsum = 0.f;
#pragma unroll
        for (int c = 0; c < 8; ++c) {
            const int gj = j0 + c * 16 + l15;
            float d2 = sqi[r] + sqj[c] - 2.f * acc[c][r];
            d2 = fmaxf(d2, 0.f);
            const float ker = __expf(-d2 * inv_sigma);
            const float mv = (gj < nb) ? mi : 0.f;
            const float o = (w0 * ain[c] + w1 * ker) * mv;
            adj_out[((size_t)(bN + gi) << 11) + gj] = o;
            rsum += o;
        }
        rsum += __shfl_xor(rsum, 1);
        rsum += __shfl_xor(rsum, 2);
        rsum += __shfl_xor(rsum, 4);
        rsum += __shfl_xor(rsum, 8);
        if (l15 == 0) atomicAdd(&deg[bN + gi], rsum);
    }
}

// ---------------------------------------------------------------------------
// Kernel 4: op_adj = adj @ emb_n via plain bf16 MFMA.  Block: 64 i-rows x
// 512-j chunk x full F=64; 4 waves (wave w: C rows w*16..+16, cols 0..64).
// adj tile -> bf16 LDS [i][j] (pad 72); emb_n tile -> bf16 LDS TRANSPOSED
// [f][j] (pad 72) so B-frag reads are contiguous.  Atomic accumulate into
// the emb region of d_out (pre-zeroed).
// ---------------------------------------------------------------------------
__global__ __launch_bounds__(256, 4) void k_opadj(const float* __restrict__ adj,
                                                  const float* __restrict__ emb,
                                                  const float* __restrict__ meanp,
                                                  const float* __restrict__ rstdp,
                                                  const int* __restrict__ nbp,
                                                  float* __restrict__ opadj) {
    __shared__ __align__(16) unsigned short As[64][72];
    __shared__ __align__(16) unsigned short Bt[64][72];

    const int b  = blockIdx.z;
    const int i0 = blockIdx.x << 6;
    const int nb = nbp[b];
    if (i0 >= nb) return;
    const int jbeg = blockIdx.y << 9;
    if (jbeg >= nb) return;
    const int jend = min(jbeg + 512, (nb + 63) & ~63);

    const int bN = b * NN;
    const int tid = threadIdx.x;
    const int w = tid >> 6, lane = tid & 63;
    const int l15 = lane & 15, lq = lane >> 4;

    const int sjj = tid & 63;           // Bt staging: j within tile
    const int fb  = (tid >> 6) << 4;    // Bt staging: f block (16 f's)
    float mn[16], rs[16];
#pragma unroll
    for (int e = 0; e < 16; e += 4) {
        *(float4*)&mn[e] = *(const float4*)(meanp + (b << 6) + fb + e);
        *(float4*)&rs[e] = *(const float4*)(rstdp + (b << 6) + fb + e);
    }

    f32x4 acc[4];
#pragma unroll
    for (int c = 0; c < 4; ++c) acc[c] = (f32x4){0.f, 0.f, 0.f, 0.f};

    for (int jt = jbeg; jt < jend; jt += 64) {
        // stage As: adj rows -> bf16; thread: row = t>>2, jc = (t&3)*16
        {
            const int row = tid >> 2, jc = (tid & 3) << 4;
            const float* src = adj + ((size_t)(bN + i0 + row) << 11) + jt + jc;
            __align__(16) float xv[16];
            *(float4*)(xv + 0)  = *(const float4*)(src + 0);
            *(float4*)(xv + 4)  = *(const float4*)(src + 4);
            *(float4*)(xv + 8)  = *(const float4*)(src + 8);
            *(float4*)(xv + 12) = *(const float4*)(src + 12);
            __align__(16) unsigned short hh[16];
#pragma unroll
            for (int e = 0; e < 16; ++e) hh[e] = f2bf(xv[e]);
            *(bf16x8*)&As[row][jc]     = *(bf16x8*)&hh[0];
            *(bf16x8*)&As[row][jc + 8] = *(bf16x8*)&hh[8];
        }
        // stage Bt: emb_n transposed [f][j]; thread: j = sjj, f = fb..fb+16
        {
            const float msk = (jt + sjj < nb) ? 1.f : 0.f;
            const float* src = emb + ((size_t)(bN + jt + sjj) << 6) + fb;
            __align__(16) float xv[16];
            *(float4*)(xv + 0)  = *(const float4*)(src + 0);
            *(float4*)(xv + 4)  = *(const float4*)(src + 4);
            *(float4*)(xv + 8)  = *(const float4*)(src + 8);
            *(float4*)(xv + 12) = *(const float4*)(src + 12);
#pragma unroll
            for (int e = 0; e < 16; ++e) {
                const float en = (xv[e] - mn[e]) * rs[e] * msk;
                Bt[fb + e][sjj] = f2bf(en);
            }
        }
        __syncthreads();
#pragma unroll
        for (int ks = 0; ks < 2; ++ks) {
            const bf16x8 a = *(bf16x8*)&As[w * 16 + l15][ks * 32 + lq * 8];
#pragma unroll
            for (int c = 0; c < 4; ++c) {
                const bf16x8 bv = *(bf16x8*)&Bt[c * 16 + l15][ks * 32 + lq * 8];
                acc[c] = __builtin_amdgcn_mfma_f32_16x16x32_bf16(a, bv, acc[c], 0, 0, 0);
            }
        }
        __syncthreads();
    }

#pragma unroll
    for (int c = 0; c < 4; ++c)
#pragma unroll
        for (int r = 0; r < 4; ++r) {
            const int gi = i0 + w * 16 + lq * 4 + r;
            atomicAdd(opadj + ((size_t)(bN + gi) << 6) + c * 16 + l15, acc[c][r]);
        }
}

// ---------------------------------------------------------------------------
// Kernel 5: epilogue.  Reads op_adj (emb region of d_out) + deg, builds
// [op_deg | op_adj], conv matmul, nu matmul, relu; overwrites emb_out rows.
// ---------------------------------------------------------------------------
__global__ __launch_bounds__(256) void k_epilogue(const float* __restrict__ emb,
                                                  const float* __restrict__ meanp,
                                                  const float* __restrict__ rstdp,
                                                  const float* __restrict__ degp,
                                                  const int* __restrict__ nbp,
                                                  const float* __restrict__ convW,
                                                  const float* __restrict__ convB,
                                                  const float* __restrict__ nuW,
                                                  const float* __restrict__ nuB,
                                                  float* __restrict__ emb_out) {
    __shared__ __align__(16) float smem[13056];
    float* xs = smem;          // [64][132] [i][op_deg|op_adj]
    float* us = smem + 8704;   // [64][68] emb_upd
    float* es = smem;          // reuse: [64][68] emb_in rows

    const int b   = blockIdx.y;
    const int i0  = blockIdx.x << 6;
    const int tid = threadIdx.x;
    const int tx = tid & 15, ty = tid >> 4;
    const int nb = nbp[b];
    const int bN = b * NN;
    const int sj  = tid >> 2;
    const int scb = (tid & 3) << 4;

    {
        const float4 m4 = *(const float4*)(meanp + (b << 6) + (tx << 2));
        const float4 r4 = *(const float4*)(rstdp + (b << 6) + (tx << 2));
#pragma unroll
        for (int u = 0; u < 4; ++u) {
            const int il = (ty << 2) + u;
            const int gi = i0 + il;
            const float msk = (gi < nb) ? 1.f : 0.f;
            const float dg = degp[bN + gi];
            const float4 v = *(const float4*)(emb + ((size_t)(bN + gi) << 6) + (tx << 2));
            float4 en;
            en.x = (v.x - m4.x) * r4.x * msk;
            en.y = (v.y - m4.y) * r4.y * msk;
            en.z = (v.z - m4.z) * r4.z * msk;
            en.w = (v.w - m4.w) * r4.w * msk;
            float4 od;
            od.x = dg * en.x; od.y = dg * en.y; od.z = dg * en.z; od.w = dg * en.w;
            *(float4*)&xs[il * 132 + (tx << 2)] = od;
            const float4 oa = *(const float4*)(emb_out + ((size_t)(bN + gi) << 6) + (tx << 2));
            *(float4*)&xs[il * 132 + 64 + (tx << 2)] = oa;
        }
    }
    __syncthreads();

    {
        float u4[4][4];
#pragma unroll
        for (int r = 0; r < 4; ++r)
#pragma unroll
            for (int c = 0; c < 4; ++c) u4[r][c] = 0.f;
        for (int fis = 0; fis < 128; fis += 4) {
            const float4 w0v = *(const float4*)(convW + ((fis + 0) << 6) + (tx << 2));
            const float4 w1v = *(const float4*)(convW + ((fis + 1) << 6) + (tx << 2));
            const float4 w2v = *(const float4*)(convW + ((fis + 2) << 6) + (tx << 2));
            const float4 w3v = *(const float4*)(convW + ((fis + 3) << 6) + (tx << 2));
#pragma unroll
            for (int r = 0; r < 4; ++r) {
                const float4 x = *(const float4*)&xs[((ty << 2) + r) * 132 + fis];
                u4[r][0] += x.x * w0v.x + x.y * w1v.x + x.z * w2v.x + x.w * w3v.x;
                u4[r][1] += x.x * w0v.y + x.y * w1v.y + x.z * w2v.y + x.w * w3v.y;
                u4[r][2] += x.x * w0v.z + x.y * w1v.z + x.z * w2v.z + x.w * w3v.z;
                u4[r][3] += x.x * w0v.w + x.y * w1v.w + x.z * w2v.w + x.w * w3v.w;
            }
        }
        const float4 cb4 = *(const float4*)(convB + (tx << 2));
#pragma unroll
        for (int r = 0; r < 4; ++r) {
            float4 o;
            o.x = u4[r][0] + cb4.x; o.y = u4[r][1] + cb4.y;
            o.z = u4[r][2] + cb4.z; o.w = u4[r][3] + cb4.w;
            *(float4*)&us[((ty << 2) + r) * 68 + (tx << 2)] = o;
        }
    }
    __syncthreads();

    {
        const float* pe = emb + ((size_t)(bN + i0 + sj) << 6) + scb;
#pragma unroll
        for (int u = 0; u < 4; ++u)
            *(float4*)&es[sj * 68 + scb + (u << 2)] = *(const float4*)(pe + (u << 2));
    }
    __syncthreads();

    {
        float u4[4][4];
#pragma unroll
        for (int r = 0; r < 4; ++r)
#pragma unroll
            for (int c = 0; c < 4; ++c) u4[r][c] = 0.f;
        for (int fis = 0; fis < 64; fis += 4) {
            const float4 w0v = *(const float4*)(nuW + ((fis + 0) << 6) + (tx << 2));
            const float4 w1v = *(const float4*)(nuW + ((fis + 1) << 6) + (tx << 2));
            const float4 w2v = *(const float4*)(nuW + ((fis + 2) << 6) + (tx << 2));
            const float4 w3v = *(const float4*)(nuW + ((fis + 3) << 6) + (tx << 2));
#pragma unroll
            for (int r = 0; r < 4; ++r) {
                const float4 x = *(const float4*)&es[((ty << 2) + r) * 68 + fis];
                u4[r][0] += x.x * w0v.x + x.y * w1v.x + x.z * w2v.x + x.w * w3v.x;
                u4[r][1] += x.x * w0v.y + x.y * w1v.y + x.z * w2v.y + x.w * w3v.y;
                u4[r][2] += x.x * w0v.z + x.y * w1v.z + x.z * w2v.z + x.w * w3v.z;
                u4[r][3] += x.x * w0v.w + x.y * w1v.w + x.z * w2v.w + x.w * w3v.w;
            }
        }
        for (int fis = 0; fis < 64; fis += 4) {
            const float4 w0v = *(const float4*)(nuW + ((64 + fis + 0) << 6) + (tx << 2));
            const float4 w1v = *(const float4*)(nuW + ((64 + fis + 1) << 6) + (tx << 2));
            const float4 w2v = *(const float4*)(nuW + ((64 + fis + 2) << 6) + (tx << 2));
            const float4 w3v = *(const float4*)(nuW + ((64 + fis + 3) << 6) + (tx << 2));
#pragma unroll
            for (int r = 0; r < 4; ++r) {
                const float4 x = *(const float4*)&us[((ty << 2) + r) * 68 + fis];
                u4[r][0] += x.x * w0v.x + x.y * w1v.x + x.z * w2v.x + x.w * w3v.x;
                u4[r][1] += x.x * w0v.y + x.y * w1v.y + x.z * w2v.y + x.w * w3v.y;
                u4[r][2] += x.x * w0v.z + x.y * w1v.z + x.z * w2v.z + x.w * w3v.z;
                u4[r][3] += x.x * w0v.w + x.y * w1v.w + x.z * w2v.w + x.w * w3v.w;
            }
        }
        const float4 nb4 = *(const float4*)(nuB + (tx << 2));
#pragma unroll
        for (int r = 0; r < 4; ++r) {
            const int gi = i0 + (ty << 2) + r;
            float4 o;
            o.x = fmaxf(u4[r][0] + nb4.x, 0.f);
            o.y = fmaxf(u4[r][1] + nb4.y, 0.f);
            o.z = fmaxf(u4[r][2] + nb4.z, 0.f);
            o.w = fmaxf(u4[r][3] + nb4.w, 0.f);
            *(float4*)(emb_out + ((size_t)(bN + gi) << 6) + (tx << 2)) = o;
        }
    }
}

// ---------------------------------------------------------------------------
extern "C" void kernel_launch(void* const* d_in, const int* in_sizes, int n_in,
                              void* d_out, int out_size, void* d_ws, size_t ws_size,
                              hipStream_t stream) {
    (void)in_sizes; (void)n_in; (void)out_size; (void)ws_size;
    const float* emb_in   = (const float*)d_in[0];
    const float* adj_in   = (const float*)d_in[1];
    const int*   nbp      = (const int*)d_in[3];
    const float* sigp     = (const float*)d_in[4];
    const float* cw       = (const float*)d_in[5];
    const float* convW    = (const float*)d_in[6];
    const float* convB    = (const float*)d_in[7];
    const float* nuW      = (const float*)d_in[8];
    const float* nuB      = (const float*)d_in[9];

    float* emb_out = (float*)d_out;
    float* adj_out = (float*)d_out + EMB_SZ;

    float* ws   = (float*)d_ws;
    float* sq   = ws + WS_SQ;
    float* asum = ws + WS_ASUM;
    float* asq  = ws + WS_ASQ;
    float* mean = ws + WS_MEAN;
    float* rstd = ws + WS_RSTD;
    float* deg  = ws + WS_DEG;

    // one memset covers asum, asq, mean, rstd (overwritten), deg
    hipMemsetAsync(asum, 0, (2 * BB * FF + 2 * BB * FF + BB * NN) * sizeof(float) / 2
                            + (BB * NN) * sizeof(float) / 1, stream);
    hipMemsetAsync(emb_out, 0, (size_t)EMB_SZ * sizeof(float), stream);

    k_stats<<<dim3(32, BB), 256, 0, stream>>>(emb_in, sq, asum, asq);
    k_finalize<<<1, BB * FF, 0, stream>>>(asum, asq, nbp, mean, rstd);
    k_adj_deg<<<dim3(NN / 128, NN / 64, BB), 256, 0, stream>>>(emb_in, adj_in, sq, sigp,
                                                               cw, nbp, adj_out, deg);
    k_opadj<<<dim3(NN / 64, 4, BB), 256, 0, stream>>>(adj_out, emb_in, mean, rstd,
                                                      nbp, emb_out);
    k_epilogue<<<dim3(NN / 64, BB), 256, 0, stream>>>(emb_in, mean, rstd, deg, nbp,
                                                      convW, convB, nuW, nuB, emb_out);
}